// Round 10
// baseline (492.279 us; speedup 1.0000x reference)
//
#include <hip/hip_runtime.h>
#include <math.h>

typedef unsigned short u16;
typedef unsigned int u32;
typedef short short8 __attribute__((ext_vector_type(8)));
typedef float f32x4 __attribute__((ext_vector_type(4)));

#define Bn 16
#define Cc 256
#define Pp 4096
#define DHc 512
#define PTOT 65536   // Bn * Pp
#define SCALE 0.25f

__device__ __forceinline__ float bf2f(u16 u) {
    return __uint_as_float(((u32)u) << 16);
}
__device__ __forceinline__ u16 f2bf(float f) {
    u32 u = __float_as_uint(f);
    u32 lsb = (u >> 16) & 1u;
    u += 0x7fffu + lsb;  // round-to-nearest-even
    return (u16)(u >> 16);
}

// global -> LDS direct copy, 16 bytes per lane (LDS dest must be base + lane*16).
__device__ __forceinline__ void gload16(const u16* g, u16* l) {
    __builtin_amdgcn_global_load_lds(
        (const __attribute__((address_space(1))) void*)(uintptr_t)g,
        (__attribute__((address_space(3))) void*)(u32)(uintptr_t)l,
        16, 0, 0);
}

// ---------------- K1: means -> bf16 xmb [2048][256]; rows 0..1023 = (b,h) row-branch,
// rows 1024..2047 = (b,w) col-branch.
__global__ __launch_bounds__(256) void mean_kernel(
    const float* __restrict__ x, u16* __restrict__ xmb) {
    __shared__ float plane[64][65];
    int bc = blockIdx.x;
    int b = bc >> 8, c = bc & 255;
    const float* xp = x + (size_t)bc * Pp;
    int tid = threadIdx.x;
#pragma unroll
    for (int k = 0; k < 16; ++k) {
        int idx = tid + k * 256;
        plane[idx >> 6][idx & 63] = xp[idx];
    }
    __syncthreads();
    if (tid < 64) {
        float s = 0.f;
#pragma unroll
        for (int w = 0; w < 64; ++w) s += plane[tid][w];
        xmb[((size_t)b * 64 + tid) * 256 + c] = f2bf(s * (1.f / 64.f));
    } else if (tid < 128) {
        int w = tid - 64;
        float s = 0.f;
#pragma unroll
        for (int h = 0; h < 64; ++h) s += plane[h][w];
        xmb[((size_t)1024 + b * 64 + w) * 256 + c] = f2bf(s * (1.f / 64.f));
    }
}

// --------------------- K2: transpose x [b][c][p] -> xbf [b*P+p][c] bf16
__global__ __launch_bounds__(256) void xpose_kernel(
    const float* __restrict__ x, u16* __restrict__ xbf) {
    __shared__ float tile[64][65];
    int pb = blockIdx.x;
    int cb = blockIdx.y;
    int b = blockIdx.z;
    int t = threadIdx.x;
    int p_l = t & 63, c_q = t >> 6;
    const float* xp = x + ((size_t)b * Cc + cb * 64) * Pp + pb * 64;
#pragma unroll
    for (int rr = 0; rr < 16; ++rr) {
        int c_l = rr * 4 + c_q;
        tile[p_l][c_l] = xp[(size_t)c_l * Pp + p_l];
    }
    __syncthreads();
    int c_l2 = t & 63, p_q = t >> 6;
    u16* dst = xbf + ((size_t)b * Pp + pb * 64) * Cc + cb * 64;
#pragma unroll
    for (int rr = 0; rr < 16; ++rr) {
        int p_l2 = rr * 4 + p_q;
        dst[(size_t)p_l2 * Cc + c_l2] = f2bf(tile[p_l2][c_l2]);
    }
}

// -------------- K3: weights fp32 -> bf16; wq/wk/wv stacked into wqkvb [768][256]
__global__ __launch_bounds__(256) void wconv_kernel(
    const float* __restrict__ wq, const float* __restrict__ wk, const float* __restrict__ wv,
    const float* __restrict__ wsc, const float* __restrict__ wproj, const float* __restrict__ wpw,
    const float* __restrict__ wrow, const float* __restrict__ wcol,
    const float* __restrict__ wdw,
    u16* __restrict__ wqkvb, u16* __restrict__ wscb,
    u16* __restrict__ wprojb, u16* __restrict__ wpwb,
    u16* __restrict__ wrb, u16* __restrict__ wcb, float* __restrict__ wdwT) {
    int t = blockIdx.x * 256 + threadIdx.x;  // 983040 total
    if (t < 2304) wdwT[(t % 9) * 256 + (t / 9)] = wdw[t];
    if (t < 32768) wqkvb[t] = f2bf(wq[t]);
    else if (t < 65536) wqkvb[t] = f2bf(wk[t - 32768]);
    else if (t < 196608) wqkvb[t] = f2bf(wv[t - 65536]);
    else if (t < 262144) wscb[t - 196608] = f2bf(wsc[t - 196608]);
    else if (t < 393216) wprojb[t - 262144] = f2bf(wproj[t - 262144]);
    else if (t < 458752) wpwb[t - 393216] = f2bf(wpw[t - 393216]);
    else if (t < 720896) wrb[t - 458752] = f2bf(wrow[t - 458752]);
    else wcb[t - 720896] = f2bf(wcol[t - 720896]);
}

// ------------------------------------------------------------- MFMA GEMM mainloop
// D[o][p] = sum_k W[o][k] * X[p][k], 128x128 tile, BK=32, 4 waves (2x2 of 64x64).
__device__ __forceinline__ void gemm_mainloop(
    const u16* __restrict__ W, const u16* __restrict__ X, int K,
    int o0, size_t prow0, u16* ldsA, u16* ldsB, f32x4 (&acc)[4][4]) {
    int t = threadIdx.x;
    int w = t >> 6, lane = t & 63;
    int sr = (w << 5) + (lane >> 2);
    int ks = (lane & 3) * 8;
    const u16* gA = W + (size_t)(o0 + sr) * K + ks;
    const u16* gB = X + (prow0 + sr) * K + ks;
    u16* lA = ldsA + sr * 32 + ks;
    u16* lB = ldsB + sr * 32 + ks;
    int wo = (w >> 1) * 64, wp = (w & 1) * 64;
    const u16* fA = ldsA + (wo + (lane & 15)) * 32 + ((lane >> 4) * 8);
    const u16* fB = ldsB + (wp + (lane & 15)) * 32 + ((lane >> 4) * 8);

    for (int k0 = 0; k0 < K; k0 += 32) {
        if (k0) __syncthreads();
        gload16(gA + k0, lA);
        gload16(gA + k0 + (size_t)16 * K, lA + 16 * 32);
        gload16(gB + k0, lB);
        gload16(gB + k0 + (size_t)16 * K, lB + 16 * 32);
        __syncthreads();
        short8 a[4], b[4];
#pragma unroll
        for (int i = 0; i < 4; ++i) a[i] = *(const short8*)(fA + i * 16 * 32);
#pragma unroll
        for (int j = 0; j < 4; ++j) b[j] = *(const short8*)(fB + j * 16 * 32);
#pragma unroll
        for (int i = 0; i < 4; ++i)
#pragma unroll
            for (int j = 0; j < 4; ++j)
                acc[i][j] = __builtin_amdgcn_mfma_f32_16x16x32_bf16(a[i], b[j], acc[i][j], 0, 0, 0);
    }
}

// ---------- K4: q/k/v embeddings as one GEMM: [768]x[2048 rows]xK=256.
__global__ __launch_bounds__(256) void gemm_qkv(
    const u16* __restrict__ Wb, const u16* __restrict__ X,
    const float* __restrict__ sq, const float* __restrict__ bq,
    const float* __restrict__ sk, const float* __restrict__ bk,
    const float* __restrict__ sv, const float* __restrict__ bv,
    const float* __restrict__ posrq, const float* __restrict__ posrk,
    const float* __restrict__ poscq, const float* __restrict__ posck,
    float* __restrict__ qrow, float* __restrict__ krow, float* __restrict__ vrow,
    float* __restrict__ qcol, float* __restrict__ kcol, float* __restrict__ vcol) {
    __shared__ u16 ldsA[128 * 32];
    __shared__ u16 ldsB[128 * 32];
    f32x4 acc[4][4];
#pragma unroll
    for (int i = 0; i < 4; ++i)
#pragma unroll
        for (int j = 0; j < 4; ++j) acc[i][j] = (f32x4){0.f, 0.f, 0.f, 0.f};
    int o0 = blockIdx.x * 128;          // 0..5
    size_t prow0 = (size_t)blockIdx.y * 128;  // 0..15
    gemm_mainloop(Wb, X, 256, o0, prow0, ldsA, ldsB, acc);

    int lane = threadIdx.x & 63, w = threadIdx.x >> 6;
    int wo = (w >> 1) * 64, wp = (w & 1) * 64;
    int quad = lane >> 4, cn = lane & 15;
#pragma unroll
    for (int j = 0; j < 4; ++j) {
        int p = (int)prow0 + wp + j * 16 + cn;
        int branch = p >> 10, loc = p & 1023;
        int b = loc >> 6, n = loc & 63;
        float coords = 0.25f * (float)n - 0.375f;
        coords = fminf(fmaxf(coords, 0.f), 15.f);
        int lo = (int)floorf(coords);
        int hi = min(lo + 1, 15);
        float tt = coords - (float)lo;
#pragma unroll
        for (int i = 0; i < 4; ++i) {
            int o = o0 + wo + i * 16 + quad * 4;
            if (o < 128) {
                const float* pos = branch ? poscq : posrq;
                float* dst = branch ? qcol : qrow;
#pragma unroll
                for (int r = 0; r < 4; ++r) {
                    int c = o + r;
                    float pv = pos[c * 16 + lo] * (1.f - tt) + pos[c * 16 + hi] * tt;
                    dst[b * 8192 + c * 64 + n] = acc[i][j][r] * sq[c] + bq[c] + pv;
                }
            } else if (o < 256) {
                const float* pos = branch ? posck : posrk;
                float* dst = branch ? kcol : krow;
#pragma unroll
                for (int r = 0; r < 4; ++r) {
                    int c = o - 128 + r;
                    float pv = pos[c * 16 + lo] * (1.f - tt) + pos[c * 16 + hi] * tt;
                    dst[b * 8192 + c * 64 + n] = acc[i][j][r] * sk[c] + bk[c] + pv;
                }
            } else {
                float* dst = branch ? vcol : vrow;
#pragma unroll
                for (int r = 0; r < 4; ++r) {
                    int c = o - 256 + r;
                    dst[b * 32768 + c * 64 + n] = acc[i][j][r] * sv[c] + bv[c];
                }
            }
        }
    }
}

// ---------------- K5: axial attention v2 — distributed scores, no 8x redundancy.
__global__ __launch_bounds__(512, 2) void attn_kernel(
    const float* __restrict__ qr, const float* __restrict__ kr, const float* __restrict__ vr,
    const float* __restrict__ qc, const float* __restrict__ kc, const float* __restrict__ vc,
    u16* __restrict__ xxbf) {
    int branch = blockIdx.y;
    const float* q = branch ? qc : qr;
    const float* k = branch ? kc : kr;
    const float* v = branch ? vc : vr;
    int bh = blockIdx.x;
    int b = bh >> 3, h = bh & 7;
    __shared__ float qs[16][64], ks[16][64], vs[64][64];
    __shared__ float sl[64][65], el[64][65];
    int t = threadIdx.x;
#pragma unroll
    for (int i = t; i < 1024; i += 512) {
        int c = i >> 6, nn = i & 63;
        qs[c][nn] = q[b * 8192 + (h * 16 + c) * 64 + nn];
        ks[c][nn] = k[b * 8192 + (h * 16 + c) * 64 + nn];
    }
#pragma unroll
    for (int i = t; i < 4096; i += 512) {
        int d = i >> 6, nn = i & 63;
        vs[d][nn] = v[b * 32768 + (h * 64 + d) * 64 + nn];
    }
    __syncthreads();

    int n = t & 63, dq = t >> 6;  // dq in [0,8)
    float qv[16];
#pragma unroll
    for (int c = 0; c < 16; ++c) qv[c] = qs[c][n];

    // QK^T: 8 m-values per thread
    float sp[8];
#pragma unroll
    for (int mm = 0; mm < 8; ++mm) {
        int m = dq * 8 + mm;
        float acc = 0.f;
#pragma unroll
        for (int c = 0; c < 16; ++c) acc += qv[c] * ks[c][m];
        sp[mm] = acc * SCALE;
        sl[n][m] = sp[mm];
    }
    __syncthreads();

    // row max (raw scores)
    float mx = -1e30f;
#pragma unroll
    for (int m = 0; m < 64; ++m) mx = fmaxf(mx, sl[n][m]);

    // own exp -> el
#pragma unroll
    for (int mm = 0; mm < 8; ++mm) el[n][dq * 8 + mm] = __expf(sp[mm] - mx);
    __syncthreads();

    // row sum + PV
    float sum = 0.f;
#pragma unroll
    for (int m = 0; m < 64; ++m) sum += el[n][m];
    float inv = 1.f / sum;

    float acc[8];
#pragma unroll
    for (int dd = 0; dd < 8; ++dd) acc[dd] = 0.f;
#pragma unroll
    for (int m = 0; m < 64; ++m) {
        float e = el[n][m];
#pragma unroll
        for (int dd = 0; dd < 8; ++dd) acc[dd] += e * vs[dq * 8 + dd][m];
    }
    u16* dst = xxbf + (((size_t)(b * 2 + branch)) * 64 + n) * 512 + h * 64 + dq * 8;
#pragma unroll
    for (int dd = 0; dd < 8; ++dd)
        dst[dd] = f2bf(fmaxf(acc[dd] * inv, 0.f));
}

// -------- K6: post cbn via MFMA. per (o-half, b, branch): M=64(n) N=256(o) K=512.
__global__ __launch_bounds__(256) void post_gemm(
    const u16* __restrict__ xxbf, const u16* __restrict__ wrb, const u16* __restrict__ wcb,
    const float* __restrict__ s_row, const float* __restrict__ b_row,
    const float* __restrict__ s_col, const float* __restrict__ b_col,
    float* __restrict__ xr2, float* __restrict__ xc2) {
    __shared__ u16 ldsA[64 * 32];
    __shared__ u16 ldsB[256 * 32];
    int o0 = blockIdx.x * 256;
    int b = blockIdx.y;
    int branch = blockIdx.z;
    const u16* A = xxbf + ((size_t)(b * 2 + branch)) * 64 * 512;
    const u16* W = branch ? wcb : wrb;
    const float* ss = branch ? s_col : s_row;
    const float* bb = branch ? b_col : b_row;
    float* dst = (branch ? xc2 : xr2) + (size_t)b * 32768;

    f32x4 acc[4][4];
#pragma unroll
    for (int i = 0; i < 4; ++i)
#pragma unroll
        for (int j = 0; j < 4; ++j) acc[i][j] = (f32x4){0.f, 0.f, 0.f, 0.f};

    int t = threadIdx.x, w = t >> 6, lane = t & 63;
    int ks = (t & 3) * 8;
    const u16* gA = A + (size_t)(t >> 2) * 512 + ks;
    const u16* gB = W + (size_t)(o0 + (t >> 2)) * 512 + ks;
    u16* lA = ldsA + (t >> 2) * 32 + ks;
    u16* lB = ldsB + (t >> 2) * 32 + ks;
    const u16* fA = ldsA + (lane & 15) * 32 + ((lane >> 4) * 8);
    const u16* fB = ldsB + (w * 64 + (lane & 15)) * 32 + ((lane >> 4) * 8);

    for (int k0 = 0; k0 < 512; k0 += 32) {
        if (k0) __syncthreads();
        gload16(gA + k0, lA);
#pragma unroll
        for (int r = 0; r < 4; ++r)
            gload16(gB + k0 + (size_t)r * 64 * 512, lB + r * 64 * 32);
        __syncthreads();
        short8 a[4], bfr[4];
#pragma unroll
        for (int i = 0; i < 4; ++i) a[i] = *(const short8*)(fA + i * 16 * 32);
#pragma unroll
        for (int j = 0; j < 4; ++j) bfr[j] = *(const short8*)(fB + j * 16 * 32);
#pragma unroll
        for (int i = 0; i < 4; ++i)
#pragma unroll
            for (int j = 0; j < 4; ++j)
                acc[i][j] = __builtin_amdgcn_mfma_f32_16x16x32_bf16(a[i], bfr[j], acc[i][j], 0, 0, 0);
    }

    int quad = lane >> 4, cn = lane & 15;
#pragma unroll
    for (int i = 0; i < 4; ++i)
#pragma unroll
        for (int j = 0; j < 4; ++j) {
            int o = o0 + w * 64 + j * 16 + cn;
            float sv_ = ss[o], bv_ = bb[o];
#pragma unroll
            for (int r = 0; r < 4; ++r) {
                int n = i * 16 + quad * 4 + r;
                dst[n * 512 + o] = acc[i][j][r] * sv_ + bv_;
            }
        }
}

// ------------------------------------- G1: sc = cbn(x, w_sc)  -> scb bf16 [p][256]
__global__ __launch_bounds__(256) void gemm_sc(
    const u16* __restrict__ Wb, const u16* __restrict__ X,
    const float* __restrict__ s, const float* __restrict__ bb, u16* __restrict__ outb) {
    __shared__ u16 ldsA[128 * 32];
    __shared__ u16 ldsB[128 * 32];
    f32x4 acc[4][4];
#pragma unroll
    for (int i = 0; i < 4; ++i)
#pragma unroll
        for (int j = 0; j < 4; ++j) acc[i][j] = (f32x4){0.f, 0.f, 0.f, 0.f};
    int o0 = blockIdx.x * 128;
    size_t prow0 = (size_t)blockIdx.y * 128;
    gemm_mainloop(Wb, X, 256, o0, prow0, ldsA, ldsB, acc);

    int lane = threadIdx.x & 63, w = threadIdx.x >> 6;
    int wo = (w >> 1) * 64, wp = (w & 1) * 64;
    int quad = lane >> 4, cn = lane & 15;
#pragma unroll
    for (int i = 0; i < 4; ++i) {
        int ob = o0 + wo + i * 16 + quad * 4;
        f32x4 s4 = *(const f32x4*)&s[ob];
        f32x4 b4 = *(const f32x4*)&bb[ob];
#pragma unroll
        for (int j = 0; j < 4; ++j) {
            size_t p = prow0 + wp + j * 16 + cn;
            ushort4 o4;
            o4.x = f2bf(acc[i][j][0] * s4[0] + b4[0]);
            o4.y = f2bf(acc[i][j][1] * s4[1] + b4[1]);
            o4.z = f2bf(acc[i][j][2] * s4[2] + b4[2]);
            o4.w = f2bf(acc[i][j][3] * s4[3] + b4[3]);
            *(ushort4*)&outb[p * 256 + ob] = o4;
        }
    }
}

// ------------- FUSED DW+PW: one block = 64 p-rows (= one (b,h) row, all w).
__global__ __launch_bounds__(512, 4) void fused_dwpw(
    const u16* __restrict__ sc, const float* __restrict__ wdwT,
    const float* __restrict__ sdw, const float* __restrict__ bdw,
    const u16* __restrict__ Wpw,
    const float* __restrict__ spw, const float* __restrict__ bpw,
    u16* __restrict__ gate) {
    __shared__ u16 dwt[64 * 256];  // 32 KiB swizzled dw-output tile

    int t = threadIdx.x;
    int lane = t & 63, w = t >> 6;
    int quad = lane >> 4, cn = lane & 15;
    int p0 = blockIdx.x * 64;
    int h = (p0 >> 6) & 63;  // uniform over block

    // ---------------- phase A: dw 3x3, 4 (p,8ch) tasks per thread
#pragma unroll
    for (int kq = 0; kq < 4; ++kq) {
        int task = t + kq * 512;        // 0..2047
        int p_l = task >> 5;            // 0..63 == w index
        int cg = (task & 31) * 8;       // channel octet base
        size_t p = (size_t)p0 + p_l;
        float acc[8] = {0.f, 0.f, 0.f, 0.f, 0.f, 0.f, 0.f, 0.f};
#pragma unroll
        for (int ky = 0; ky < 3; ++ky) {
            int hh = h + ky - 1;
            if (hh < 0 || hh > 63) continue;
#pragma unroll
            for (int kx = 0; kx < 3; ++kx) {
                int wx = p_l + kx - 1;
                if (wx < 0 || wx > 63) continue;
                size_t pp = (size_t)((long long)p + (ky - 1) * 64 + (kx - 1));
                short8 v = *(const short8*)&sc[pp * 256 + cg];
                const float* wt = &wdwT[(ky * 3 + kx) * 256 + cg];
                f32x4 w0 = *(const f32x4*)wt;
                f32x4 w1 = *(const f32x4*)(wt + 4);
                acc[0] += w0[0] * bf2f((u16)v[0]); acc[1] += w0[1] * bf2f((u16)v[1]);
                acc[2] += w0[2] * bf2f((u16)v[2]); acc[3] += w0[3] * bf2f((u16)v[3]);
                acc[4] += w1[0] * bf2f((u16)v[4]); acc[5] += w1[1] * bf2f((u16)v[5]);
                acc[6] += w1[2] * bf2f((u16)v[6]); acc[7] += w1[3] * bf2f((u16)v[7]);
            }
        }
        f32x4 s0 = *(const f32x4*)&sdw[cg], s1 = *(const f32x4*)&sdw[cg + 4];
        f32x4 b0 = *(const f32x4*)&bdw[cg], b1 = *(const f32x4*)&bdw[cg + 4];
        short8 o;
        o[0] = (short)f2bf(fmaxf(acc[0] * s0[0] + b0[0], 0.f));
        o[1] = (short)f2bf(fmaxf(acc[1] * s0[1] + b0[1], 0.f));
        o[2] = (short)f2bf(fmaxf(acc[2] * s0[2] + b0[2], 0.f));
        o[3] = (short)f2bf(fmaxf(acc[3] * s0[3] + b0[3], 0.f));
        o[4] = (short)f2bf(fmaxf(acc[4] * s1[0] + b1[0], 0.f));
        o[5] = (short)f2bf(fmaxf(acc[5] * s1[1] + b1[1], 0.f));
        o[6] = (short)f2bf(fmaxf(acc[6] * s1[2] + b1[2], 0.f));
        o[7] = (short)f2bf(fmaxf(acc[7] * s1[3] + b1[3], 0.f));
        int ko = cg >> 3;  // octet index 0..31
        *(short8*)&dwt[p_l * 256 + ((ko ^ (p_l & 7)) << 3)] = o;
    }
    __syncthreads();

    // ---------------- phase B: pw GEMM, wave w owns 32 o-rows x 64 p, K=256
    f32x4 acc2[2][4];
#pragma unroll
    for (int i = 0; i < 2; ++i)
#pragma unroll
        for (int j = 0; j < 4; ++j) acc2[i][j] = (f32x4){0.f, 0.f, 0.f, 0.f};

    int ow = w * 32;
    const u16* gA = Wpw + (size_t)(ow + cn) * 256 + quad * 8;

    for (int k0 = 0; k0 < 256; k0 += 32) {
        short8 a[2], b[4];
        a[0] = *(const short8*)(gA + k0);
        a[1] = *(const short8*)(gA + (size_t)16 * 256 + k0);
        int og = (k0 >> 3) + quad;
#pragma unroll
        for (int j = 0; j < 4; ++j) {
            int pl = j * 16 + cn;
            b[j] = *(const short8*)&dwt[pl * 256 + ((og ^ (pl & 7)) << 3)];
        }
#pragma unroll
        for (int i = 0; i < 2; ++i)
#pragma unroll
            for (int j = 0; j < 4; ++j)
                acc2[i][j] = __builtin_amdgcn_mfma_f32_16x16x32_bf16(a[i], b[j], acc2[i][j], 0, 0, 0);
    }

    // epilogue: h_sigmoid -> gate bf16 [p][256]
#pragma unroll
    for (int i = 0; i < 2; ++i) {
        int ob = ow + i * 16 + quad * 4;
        f32x4 s4 = *(const f32x4*)&spw[ob];
        f32x4 b4 = *(const f32x4*)&bpw[ob];
#pragma unroll
        for (int j = 0; j < 4; ++j) {
            size_t p = (size_t)p0 + j * 16 + cn;
            ushort4 o4;
            o4.x = f2bf(fminf(fmaxf(acc2[i][j][0] * s4[0] + b4[0] + 3.f, 0.f), 6.f) * (1.f / 6.f));
            o4.y = f2bf(fminf(fmaxf(acc2[i][j][1] * s4[1] + b4[1] + 3.f, 0.f), 6.f) * (1.f / 6.f));
            o4.z = f2bf(fminf(fmaxf(acc2[i][j][2] * s4[2] + b4[2] + 3.f, 0.f), 6.f) * (1.f / 6.f));
            o4.w = f2bf(fminf(fmaxf(acc2[i][j][3] * s4[3] + b4[3] + 3.f, 0.f), 6.f) * (1.f / 6.f));
            *(ushort4*)&gate[p * 256 + ob] = o4;
        }
    }
}

// ------------- FUSED v6: persistent 4-tile blocks (grid 256, 1 block/CU).
// Each block processes 4 consecutive 64-p tiles with v5's inner structure.
// Weight set (Wv 256KB + Wp 256KB) is identical across the 4 tiles -> tiles
// 1-3 hit hot L2 instead of re-fetching at HBM/L3 rate (the measured v3->v4
// lever: weight bytes dominate this kernel's time).
__global__ __launch_bounds__(512, 2) void fused_vproj(
    const u16* __restrict__ Wv, const u16* __restrict__ Wp,
    const u16* __restrict__ X,
    const float* __restrict__ sv, const float* __restrict__ bv,
    const float* __restrict__ xr2, const float* __restrict__ xc2,
    const float* __restrict__ sp, const float* __restrict__ bp,
    const u16* __restrict__ gate, float* __restrict__ out) {
    __shared__ u16 lds[64 * 512];  // 64 KiB; bytes [0,32K) = X-tile during phase 1

    int t = threadIdx.x;
    int lane = t & 63, w = t >> 6;
    int quad = lane >> 4, cn = lane & 15;

    for (int tt = 0; tt < 4; ++tt) {
        int p0 = (blockIdx.x * 4 + tt) * 64;
        int bi = p0 >> 12;
        int hh = (p0 >> 6) & 63;

        // ---- stage X tile [64 p][32 k-octets]; LDS[p][ko] = G[p][ko ^ (p&7)]
#pragma unroll
        for (int r = 0; r < 4; ++r) {
            int li = r * 512 + t;  // 16B-unit index 0..2047
            int p = li >> 5, ko = li & 31;
            gload16(X + ((size_t)(p0 + p)) * 256 + ((ko ^ (p & 7)) << 3),
                    lds + (size_t)li * 8);
        }
        __syncthreads();

        // ---------------- phase 1: V-GEMM, 8 waves x (64o x 64p), K=256.
        f32x4 acc1[4][4];
#pragma unroll
        for (int i = 0; i < 4; ++i)
#pragma unroll
            for (int j = 0; j < 4; ++j) acc1[i][j] = (f32x4){0.f, 0.f, 0.f, 0.f};

        int ow = w * 64;
        const u16* gA = Wv + (size_t)(ow + cn) * 256 + quad * 8;

        short8 a_c[4];
#pragma unroll
        for (int i = 0; i < 4; ++i) a_c[i] = *(const short8*)(gA + (size_t)i * 16 * 256);

#pragma unroll
        for (int kk = 0; kk < 8; ++kk) {
            int k0 = kk * 32;
            short8 a_n[4];
            if (kk < 7) {
#pragma unroll
                for (int i = 0; i < 4; ++i)
                    a_n[i] = *(const short8*)(gA + (size_t)i * 16 * 256 + k0 + 32);
            }
            int og = (k0 >> 3) + quad;
            short8 b[4];
#pragma unroll
            for (int j = 0; j < 4; ++j) {
                int pl = j * 16 + cn;
                b[j] = *(const short8*)&lds[pl * 256 + ((og ^ (pl & 7)) << 3)];
            }
#pragma unroll
            for (int i = 0; i < 4; ++i)
#pragma unroll
                for (int j = 0; j < 4; ++j)
                    acc1[i][j] = __builtin_amdgcn_mfma_f32_16x16x32_bf16(a_c[i], b[j], acc1[i][j], 0, 0, 0);
            if (kk < 7) {
#pragma unroll
                for (int i = 0; i < 4; ++i) a_c[i] = a_n[i];
            }
        }

        __syncthreads();  // all X reads done; abt may overwrite the region

        // epilogue 1: + sv/bv + xr + xc, relu -> bf16 -> swizzled abt
#pragma unroll
        for (int i = 0; i < 4; ++i) {
            int ob = ow + i * 16 + quad * 4;
            f32x4 s4 = *(const f32x4*)&sv[ob];
            f32x4 b4 = *(const f32x4*)&bv[ob];
            f32x4 ra = *(const f32x4*)&xr2[(size_t)bi * 32768 + hh * 512 + ob];
#pragma unroll
            for (int j = 0; j < 4; ++j) {
                int p = j * 16 + cn;  // local p == ww (p0 is 64-aligned)
                f32x4 ca = *(const f32x4*)&xc2[(size_t)bi * 32768 + p * 512 + ob];
                ushort4 o4;
                o4.x = f2bf(fmaxf(acc1[i][j][0] * s4[0] + b4[0] + ra[0] + ca[0], 0.f));
                o4.y = f2bf(fmaxf(acc1[i][j][1] * s4[1] + b4[1] + ra[1] + ca[1], 0.f));
                o4.z = f2bf(fmaxf(acc1[i][j][2] * s4[2] + b4[2] + ra[2] + ca[2], 0.f));
                o4.w = f2bf(fmaxf(acc1[i][j][3] * s4[3] + b4[3] + ra[3] + ca[3], 0.f));
                *(ushort4*)&lds[p * 512 + (ob ^ ((p & 7) << 3))] = o4;
            }
        }
        __syncthreads();  // abt complete

        // ---------------- phase 2: proj GEMM, 8 waves x (32o2 x 64p), K=512.
        f32x4 acc2[2][4];
#pragma unroll
        for (int i = 0; i < 2; ++i)
#pragma unroll
            for (int j = 0; j < 4; ++j) acc2[i][j] = (f32x4){0.f, 0.f, 0.f, 0.f};

        int o2w = w * 32;
        const u16* gP = Wp + (size_t)(o2w + cn) * 512 + quad * 8;

        short8 a2_c[2], b2_c[4];
#pragma unroll
        for (int i = 0; i < 2; ++i) a2_c[i] = *(const short8*)(gP + (size_t)i * 16 * 512);
        {
            int kk0 = quad * 8;
#pragma unroll
            for (int j = 0; j < 4; ++j) {
                int p = j * 16 + cn;
                b2_c[j] = *(const short8*)&lds[p * 512 + (kk0 ^ ((p & 7) << 3))];
            }
        }

#pragma unroll
        for (int kk = 0; kk < 16; ++kk) {
            short8 a2_n[2], b2_n[4];
            if (kk < 15) {
                int k1 = kk * 32 + 32;
#pragma unroll
                for (int i = 0; i < 2; ++i)
                    a2_n[i] = *(const short8*)(gP + (size_t)i * 16 * 512 + k1);
                int kn = k1 + quad * 8;
#pragma unroll
                for (int j = 0; j < 4; ++j) {
                    int p = j * 16 + cn;
                    b2_n[j] = *(const short8*)&lds[p * 512 + (kn ^ ((p & 7) << 3))];
                }
            }
#pragma unroll
            for (int i = 0; i < 2; ++i)
#pragma unroll
                for (int j = 0; j < 4; ++j)
                    acc2[i][j] = __builtin_amdgcn_mfma_f32_16x16x32_bf16(a2_c[i], b2_c[j], acc2[i][j], 0, 0, 0);
            if (kk < 15) {
#pragma unroll
                for (int i = 0; i < 2; ++i) a2_c[i] = a2_n[i];
#pragma unroll
                for (int j = 0; j < 4; ++j) b2_c[j] = b2_n[j];
            }
        }

        // epilogue 2: gate * (acc*s + b) -> out[b][o][p] fp32
        int pl0 = p0 & 4095;
#pragma unroll
        for (int i = 0; i < 2; ++i) {
            int ob = o2w + i * 16 + quad * 4;
            f32x4 s4 = *(const f32x4*)&sp[ob];
            f32x4 b4 = *(const f32x4*)&bp[ob];
#pragma unroll
            for (int j = 0; j < 4; ++j) {
                int p = j * 16 + cn;
                size_t pg = (size_t)p0 + p;
                ushort4 gv = *(const ushort4*)&gate[pg * 256 + ob];
                float* op = out + (size_t)bi * 1048576 + (size_t)ob * 4096 + (pl0 + p);
                op[0 * 4096] = bf2f(gv.x) * (acc2[i][j][0] * s4[0] + b4[0]);
                op[1 * 4096] = bf2f(gv.y) * (acc2[i][j][1] * s4[1] + b4[1]);
                op[2 * 4096] = bf2f(gv.z) * (acc2[i][j][2] * s4[2] + b4[2]);
                op[3 * 4096] = bf2f(gv.w) * (acc2[i][j][3] * s4[3] + b4[3]);
            }
        }
        __syncthreads();  // lds (abt) reads done before next tile's X staging
    }
}

extern "C" void kernel_launch(void* const* d_in, const int* in_sizes, int n_in,
                              void* d_out, int out_size, void* d_ws, size_t ws_size,
                              hipStream_t stream) {
    const float* x = (const float*)d_in[0];
    const float* wq = (const float*)d_in[1];
    const float* sq = (const float*)d_in[2];
    const float* bq = (const float*)d_in[3];
    const float* wk = (const float*)d_in[4];
    const float* sk = (const float*)d_in[5];
    const float* bk = (const float*)d_in[6];
    const float* wv = (const float*)d_in[7];
    const float* sv = (const float*)d_in[8];
    const float* bv = (const float*)d_in[9];
    const float* posrq = (const float*)d_in[10];
    const float* posrk = (const float*)d_in[11];
    const float* poscq = (const float*)d_in[12];
    const float* posck = (const float*)d_in[13];
    const float* w_row = (const float*)d_in[14];
    const float* s_row = (const float*)d_in[15];
    const float* b_row = (const float*)d_in[16];
    const float* w_col = (const float*)d_in[17];
    const float* s_col = (const float*)d_in[18];
    const float* b_col = (const float*)d_in[19];
    const float* w_proj = (const float*)d_in[20];
    const float* s_proj = (const float*)d_in[21];
    const float* b_proj = (const float*)d_in[22];
    const float* w_sc = (const float*)d_in[23];
    const float* s_sc = (const float*)d_in[24];
    const float* b_sc = (const float*)d_in[25];
    const float* w_dw = (const float*)d_in[26];
    const float* s_dw = (const float*)d_in[27];
    const float* b_dw = (const float*)d_in[28];
    const float* w_pw = (const float*)d_in[29];
    const float* s_pw = (const float*)d_in[30];
    const float* b_pw = (const float*)d_in[31];
    float* out = (float*)d_out;

    float* fws = (float*)d_ws;
    float* qrow = fws;                   // [b][c=128][n] fp32
    float* krow = qrow + 131072;
    float* qcol = krow + 131072;
    float* kcol = qcol + 131072;
    float* vrow = kcol + 131072;         // [b][c=512][n]
    float* vcol = vrow + 524288;
    float* xr2  = vcol + 524288;         // [b][n][512] fp32
    float* xc2  = xr2 + 524288;
    float* wdwT = xc2 + 524288;          // [9][256]
    u16* xmb    = (u16*)(wdwT + 2304);            // [2048][256] bf16 means
    u16* xbf    = xmb + 524288;                   // [65536][256]
    u16* wqkvb  = xbf + (size_t)PTOT * 256;       // [768][256]
    u16* wscb   = wqkvb + 196608;                 // [256][256]
    u16* wprojb = wscb + 65536;                   // [256][512]
    u16* wpwb   = wprojb + 131072;                // [256][256]
    u16* wrb    = wpwb + 65536;                   // [512][512]
    u16* wcb    = wrb + 262144;                   // [512][512]
    u16* xxbf   = wcb + 262144;                   // [b][br][64][512]
    u16* scb    = xxbf + 1048576;                 // [65536][256]
    u16* gate   = scb + (size_t)PTOT * 256;       // [65536][256]

    mean_kernel<<<dim3(Bn * Cc), 256, 0, stream>>>(x, xmb);
    xpose_kernel<<<dim3(64, 4, Bn), 256, 0, stream>>>(x, xbf);
    wconv_kernel<<<dim3(3840), 256, 0, stream>>>(
        wq, wk, wv, w_sc, w_proj, w_pw, w_row, w_col, w_dw,
        wqkvb, wscb, wprojb, wpwb, wrb, wcb, wdwT);
    gemm_qkv<<<dim3(6, 16), 256, 0, stream>>>(
        wqkvb, xmb, sq, bq, sk, bk, sv, bv,
        posrq, posrk, poscq, posck, qrow, krow, vrow, qcol, kcol, vcol);
    attn_kernel<<<dim3(128, 2), 512, 0, stream>>>(qrow, krow, vrow, qcol, kcol, vcol, xxbf);
    post_gemm<<<dim3(2, Bn, 2), 256, 0, stream>>>(
        xxbf, wrb, wcb, s_row, b_row, s_col, b_col, xr2, xc2);
    gemm_sc<<<dim3(2, 512), 256, 0, stream>>>(wscb, xbf, s_sc, b_sc, scb);
    fused_dwpw<<<dim3(1024), 512, 0, stream>>>(
        scb, wdwT, s_dw, b_dw, wpwb, s_pw, b_pw, gate);
    fused_vproj<<<dim3(256), 512, 0, stream>>>(
        wqkvb + 65536, wprojb, xbf, sv, bv, xr2, xc2, s_proj, b_proj, gate, out);
}

// Round 11
// 388.929 us; speedup vs baseline: 1.2657x; 1.2657x over previous
//
#include <hip/hip_runtime.h>
#include <math.h>

typedef unsigned short u16;
typedef unsigned int u32;
typedef short short8 __attribute__((ext_vector_type(8)));
typedef float f32x4 __attribute__((ext_vector_type(4)));

#define Bn 16
#define Cc 256
#define Pp 4096
#define DHc 512
#define PTOT 65536   // Bn * Pp
#define SCALE 0.25f

__device__ __forceinline__ float bf2f(u16 u) {
    return __uint_as_float(((u32)u) << 16);
}
__device__ __forceinline__ u16 f2bf(float f) {
    u32 u = __float_as_uint(f);
    u32 lsb = (u >> 16) & 1u;
    u += 0x7fffu + lsb;  // round-to-nearest-even
    return (u16)(u >> 16);
}

// global -> LDS direct copy, 16 bytes per lane (LDS dest must be base + lane*16).
__device__ __forceinline__ void gload16(const u16* g, u16* l) {
    __builtin_amdgcn_global_load_lds(
        (const __attribute__((address_space(1))) void*)(uintptr_t)g,
        (__attribute__((address_space(3))) void*)(u32)(uintptr_t)l,
        16, 0, 0);
}

// ---------------- K1: means -> bf16 xmb [2048][256]; rows 0..1023 = (b,h) row-branch,
// rows 1024..2047 = (b,w) col-branch.
__global__ __launch_bounds__(256) void mean_kernel(
    const float* __restrict__ x, u16* __restrict__ xmb) {
    __shared__ float plane[64][65];
    int bc = blockIdx.x;
    int b = bc >> 8, c = bc & 255;
    const float* xp = x + (size_t)bc * Pp;
    int tid = threadIdx.x;
#pragma unroll
    for (int k = 0; k < 16; ++k) {
        int idx = tid + k * 256;
        plane[idx >> 6][idx & 63] = xp[idx];
    }
    __syncthreads();
    if (tid < 64) {
        float s = 0.f;
#pragma unroll
        for (int w = 0; w < 64; ++w) s += plane[tid][w];
        xmb[((size_t)b * 64 + tid) * 256 + c] = f2bf(s * (1.f / 64.f));
    } else if (tid < 128) {
        int w = tid - 64;
        float s = 0.f;
#pragma unroll
        for (int h = 0; h < 64; ++h) s += plane[h][w];
        xmb[((size_t)1024 + b * 64 + w) * 256 + c] = f2bf(s * (1.f / 64.f));
    }
}

// --------------------- K2: transpose x [b][c][p] -> xbf [b*P+p][c] bf16
__global__ __launch_bounds__(256) void xpose_kernel(
    const float* __restrict__ x, u16* __restrict__ xbf) {
    __shared__ float tile[64][65];
    int pb = blockIdx.x;
    int cb = blockIdx.y;
    int b = blockIdx.z;
    int t = threadIdx.x;
    int p_l = t & 63, c_q = t >> 6;
    const float* xp = x + ((size_t)b * Cc + cb * 64) * Pp + pb * 64;
#pragma unroll
    for (int rr = 0; rr < 16; ++rr) {
        int c_l = rr * 4 + c_q;
        tile[p_l][c_l] = xp[(size_t)c_l * Pp + p_l];
    }
    __syncthreads();
    int c_l2 = t & 63, p_q = t >> 6;
    u16* dst = xbf + ((size_t)b * Pp + pb * 64) * Cc + cb * 64;
#pragma unroll
    for (int rr = 0; rr < 16; ++rr) {
        int p_l2 = rr * 4 + p_q;
        dst[(size_t)p_l2 * Cc + c_l2] = f2bf(tile[p_l2][c_l2]);
    }
}

// -------------- K3: weights fp32 -> bf16; wq/wk/wv stacked into wqkvb [768][256]
__global__ __launch_bounds__(256) void wconv_kernel(
    const float* __restrict__ wq, const float* __restrict__ wk, const float* __restrict__ wv,
    const float* __restrict__ wsc, const float* __restrict__ wproj, const float* __restrict__ wpw,
    const float* __restrict__ wrow, const float* __restrict__ wcol,
    const float* __restrict__ wdw,
    u16* __restrict__ wqkvb, u16* __restrict__ wscb,
    u16* __restrict__ wprojb, u16* __restrict__ wpwb,
    u16* __restrict__ wrb, u16* __restrict__ wcb, float* __restrict__ wdwT) {
    int t = blockIdx.x * 256 + threadIdx.x;  // 983040 total
    if (t < 2304) wdwT[(t % 9) * 256 + (t / 9)] = wdw[t];
    if (t < 32768) wqkvb[t] = f2bf(wq[t]);
    else if (t < 65536) wqkvb[t] = f2bf(wk[t - 32768]);
    else if (t < 196608) wqkvb[t] = f2bf(wv[t - 65536]);
    else if (t < 262144) wscb[t - 196608] = f2bf(wsc[t - 196608]);
    else if (t < 393216) wprojb[t - 262144] = f2bf(wproj[t - 262144]);
    else if (t < 458752) wpwb[t - 393216] = f2bf(wpw[t - 393216]);
    else if (t < 720896) wrb[t - 458752] = f2bf(wrow[t - 458752]);
    else wcb[t - 720896] = f2bf(wcol[t - 720896]);
}

// ------------------------------------------------------------- MFMA GEMM mainloop
// D[o][p] = sum_k W[o][k] * X[p][k], 128x128 tile, BK=32, 4 waves (2x2 of 64x64).
__device__ __forceinline__ void gemm_mainloop(
    const u16* __restrict__ W, const u16* __restrict__ X, int K,
    int o0, size_t prow0, u16* ldsA, u16* ldsB, f32x4 (&acc)[4][4]) {
    int t = threadIdx.x;
    int w = t >> 6, lane = t & 63;
    int sr = (w << 5) + (lane >> 2);
    int ks = (lane & 3) * 8;
    const u16* gA = W + (size_t)(o0 + sr) * K + ks;
    const u16* gB = X + (prow0 + sr) * K + ks;
    u16* lA = ldsA + sr * 32 + ks;
    u16* lB = ldsB + sr * 32 + ks;
    int wo = (w >> 1) * 64, wp = (w & 1) * 64;
    const u16* fA = ldsA + (wo + (lane & 15)) * 32 + ((lane >> 4) * 8);
    const u16* fB = ldsB + (wp + (lane & 15)) * 32 + ((lane >> 4) * 8);

    for (int k0 = 0; k0 < K; k0 += 32) {
        if (k0) __syncthreads();
        gload16(gA + k0, lA);
        gload16(gA + k0 + (size_t)16 * K, lA + 16 * 32);
        gload16(gB + k0, lB);
        gload16(gB + k0 + (size_t)16 * K, lB + 16 * 32);
        __syncthreads();
        short8 a[4], b[4];
#pragma unroll
        for (int i = 0; i < 4; ++i) a[i] = *(const short8*)(fA + i * 16 * 32);
#pragma unroll
        for (int j = 0; j < 4; ++j) b[j] = *(const short8*)(fB + j * 16 * 32);
#pragma unroll
        for (int i = 0; i < 4; ++i)
#pragma unroll
            for (int j = 0; j < 4; ++j)
                acc[i][j] = __builtin_amdgcn_mfma_f32_16x16x32_bf16(a[i], b[j], acc[i][j], 0, 0, 0);
    }
}

// ---------- K4: q/k/v embeddings as one GEMM: [768]x[2048 rows]xK=256.
__global__ __launch_bounds__(256) void gemm_qkv(
    const u16* __restrict__ Wb, const u16* __restrict__ X,
    const float* __restrict__ sq, const float* __restrict__ bq,
    const float* __restrict__ sk, const float* __restrict__ bk,
    const float* __restrict__ sv, const float* __restrict__ bv,
    const float* __restrict__ posrq, const float* __restrict__ posrk,
    const float* __restrict__ poscq, const float* __restrict__ posck,
    float* __restrict__ qrow, float* __restrict__ krow, float* __restrict__ vrow,
    float* __restrict__ qcol, float* __restrict__ kcol, float* __restrict__ vcol) {
    __shared__ u16 ldsA[128 * 32];
    __shared__ u16 ldsB[128 * 32];
    f32x4 acc[4][4];
#pragma unroll
    for (int i = 0; i < 4; ++i)
#pragma unroll
        for (int j = 0; j < 4; ++j) acc[i][j] = (f32x4){0.f, 0.f, 0.f, 0.f};
    int o0 = blockIdx.x * 128;          // 0..5
    size_t prow0 = (size_t)blockIdx.y * 128;  // 0..15
    gemm_mainloop(Wb, X, 256, o0, prow0, ldsA, ldsB, acc);

    int lane = threadIdx.x & 63, w = threadIdx.x >> 6;
    int wo = (w >> 1) * 64, wp = (w & 1) * 64;
    int quad = lane >> 4, cn = lane & 15;
#pragma unroll
    for (int j = 0; j < 4; ++j) {
        int p = (int)prow0 + wp + j * 16 + cn;
        int branch = p >> 10, loc = p & 1023;
        int b = loc >> 6, n = loc & 63;
        float coords = 0.25f * (float)n - 0.375f;
        coords = fminf(fmaxf(coords, 0.f), 15.f);
        int lo = (int)floorf(coords);
        int hi = min(lo + 1, 15);
        float tt = coords - (float)lo;
#pragma unroll
        for (int i = 0; i < 4; ++i) {
            int o = o0 + wo + i * 16 + quad * 4;
            if (o < 128) {
                const float* pos = branch ? poscq : posrq;
                float* dst = branch ? qcol : qrow;
#pragma unroll
                for (int r = 0; r < 4; ++r) {
                    int c = o + r;
                    float pv = pos[c * 16 + lo] * (1.f - tt) + pos[c * 16 + hi] * tt;
                    dst[b * 8192 + c * 64 + n] = acc[i][j][r] * sq[c] + bq[c] + pv;
                }
            } else if (o < 256) {
                const float* pos = branch ? posck : posrk;
                float* dst = branch ? kcol : krow;
#pragma unroll
                for (int r = 0; r < 4; ++r) {
                    int c = o - 128 + r;
                    float pv = pos[c * 16 + lo] * (1.f - tt) + pos[c * 16 + hi] * tt;
                    dst[b * 8192 + c * 64 + n] = acc[i][j][r] * sk[c] + bk[c] + pv;
                }
            } else {
                float* dst = branch ? vcol : vrow;
#pragma unroll
                for (int r = 0; r < 4; ++r) {
                    int c = o - 256 + r;
                    dst[b * 32768 + c * 64 + n] = acc[i][j][r] * sv[c] + bv[c];
                }
            }
        }
    }
}

// ---------------- K5: axial attention v2 — distributed scores, no 8x redundancy.
__global__ __launch_bounds__(512, 2) void attn_kernel(
    const float* __restrict__ qr, const float* __restrict__ kr, const float* __restrict__ vr,
    const float* __restrict__ qc, const float* __restrict__ kc, const float* __restrict__ vc,
    u16* __restrict__ xxbf) {
    int branch = blockIdx.y;
    const float* q = branch ? qc : qr;
    const float* k = branch ? kc : kr;
    const float* v = branch ? vc : vr;
    int bh = blockIdx.x;
    int b = bh >> 3, h = bh & 7;
    __shared__ float qs[16][64], ks[16][64], vs[64][64];
    __shared__ float sl[64][65], el[64][65];
    int t = threadIdx.x;
#pragma unroll
    for (int i = t; i < 1024; i += 512) {
        int c = i >> 6, nn = i & 63;
        qs[c][nn] = q[b * 8192 + (h * 16 + c) * 64 + nn];
        ks[c][nn] = k[b * 8192 + (h * 16 + c) * 64 + nn];
    }
#pragma unroll
    for (int i = t; i < 4096; i += 512) {
        int d = i >> 6, nn = i & 63;
        vs[d][nn] = v[b * 32768 + (h * 64 + d) * 64 + nn];
    }
    __syncthreads();

    int n = t & 63, dq = t >> 6;  // dq in [0,8)
    float qv[16];
#pragma unroll
    for (int c = 0; c < 16; ++c) qv[c] = qs[c][n];

    // QK^T: 8 m-values per thread
    float sp[8];
#pragma unroll
    for (int mm = 0; mm < 8; ++mm) {
        int m = dq * 8 + mm;
        float acc = 0.f;
#pragma unroll
        for (int c = 0; c < 16; ++c) acc += qv[c] * ks[c][m];
        sp[mm] = acc * SCALE;
        sl[n][m] = sp[mm];
    }
    __syncthreads();

    // row max (raw scores)
    float mx = -1e30f;
#pragma unroll
    for (int m = 0; m < 64; ++m) mx = fmaxf(mx, sl[n][m]);

    // own exp -> el
#pragma unroll
    for (int mm = 0; mm < 8; ++mm) el[n][dq * 8 + mm] = __expf(sp[mm] - mx);
    __syncthreads();

    // row sum + PV
    float sum = 0.f;
#pragma unroll
    for (int m = 0; m < 64; ++m) sum += el[n][m];
    float inv = 1.f / sum;

    float acc[8];
#pragma unroll
    for (int dd = 0; dd < 8; ++dd) acc[dd] = 0.f;
#pragma unroll
    for (int m = 0; m < 64; ++m) {
        float e = el[n][m];
#pragma unroll
        for (int dd = 0; dd < 8; ++dd) acc[dd] += e * vs[dq * 8 + dd][m];
    }
    u16* dst = xxbf + (((size_t)(b * 2 + branch)) * 64 + n) * 512 + h * 64 + dq * 8;
#pragma unroll
    for (int dd = 0; dd < 8; ++dd)
        dst[dd] = f2bf(fmaxf(acc[dd] * inv, 0.f));
}

// -------- K6: post cbn via MFMA. per (o-quarter, b, branch): M=64(n) N=128(o) K=512.
// o-tile 256->128 (grid 2->4 in x): 64 blocks only filled 1/4 of the CUs; 128
// blocks double concurrency on this latency-bound 2-barrier loop.
__global__ __launch_bounds__(256) void post_gemm(
    const u16* __restrict__ xxbf, const u16* __restrict__ wrb, const u16* __restrict__ wcb,
    const float* __restrict__ s_row, const float* __restrict__ b_row,
    const float* __restrict__ s_col, const float* __restrict__ b_col,
    float* __restrict__ xr2, float* __restrict__ xc2) {
    __shared__ u16 ldsA[64 * 32];
    __shared__ u16 ldsB[128 * 32];
    int o0 = blockIdx.x * 128;
    int b = blockIdx.y;
    int branch = blockIdx.z;
    const u16* A = xxbf + ((size_t)(b * 2 + branch)) * 64 * 512;
    const u16* W = branch ? wcb : wrb;
    const float* ss = branch ? s_col : s_row;
    const float* bb = branch ? b_col : b_row;
    float* dst = (branch ? xc2 : xr2) + (size_t)b * 32768;

    f32x4 acc[4][2];
#pragma unroll
    for (int i = 0; i < 4; ++i)
#pragma unroll
        for (int j = 0; j < 2; ++j) acc[i][j] = (f32x4){0.f, 0.f, 0.f, 0.f};

    int t = threadIdx.x, w = t >> 6, lane = t & 63;
    int ks = (t & 3) * 8;
    const u16* gA = A + (size_t)(t >> 2) * 512 + ks;
    const u16* gB = W + (size_t)(o0 + (t >> 2)) * 512 + ks;
    u16* lA = ldsA + (t >> 2) * 32 + ks;
    u16* lB = ldsB + (t >> 2) * 32 + ks;
    const u16* fA = ldsA + (lane & 15) * 32 + ((lane >> 4) * 8);
    const u16* fB = ldsB + (w * 32 + (lane & 15)) * 32 + ((lane >> 4) * 8);

    for (int k0 = 0; k0 < 512; k0 += 32) {
        if (k0) __syncthreads();
        gload16(gA + k0, lA);
#pragma unroll
        for (int r = 0; r < 2; ++r)
            gload16(gB + k0 + (size_t)r * 64 * 512, lB + r * 64 * 32);
        __syncthreads();
        short8 a[4], bfr[2];
#pragma unroll
        for (int i = 0; i < 4; ++i) a[i] = *(const short8*)(fA + i * 16 * 32);
#pragma unroll
        for (int j = 0; j < 2; ++j) bfr[j] = *(const short8*)(fB + j * 16 * 32);
#pragma unroll
        for (int i = 0; i < 4; ++i)
#pragma unroll
            for (int j = 0; j < 2; ++j)
                acc[i][j] = __builtin_amdgcn_mfma_f32_16x16x32_bf16(a[i], bfr[j], acc[i][j], 0, 0, 0);
    }

    int quad = lane >> 4, cn = lane & 15;
#pragma unroll
    for (int i = 0; i < 4; ++i)
#pragma unroll
        for (int j = 0; j < 2; ++j) {
            int o = o0 + w * 32 + j * 16 + cn;
            float sv_ = ss[o], bv_ = bb[o];
#pragma unroll
            for (int r = 0; r < 4; ++r) {
                int n = i * 16 + quad * 4 + r;
                dst[n * 512 + o] = acc[i][j][r] * sv_ + bv_;
            }
        }
}

// ------------------------------------- G1: sc = cbn(x, w_sc)  -> scb bf16 [p][256]
__global__ __launch_bounds__(256) void gemm_sc(
    const u16* __restrict__ Wb, const u16* __restrict__ X,
    const float* __restrict__ s, const float* __restrict__ bb, u16* __restrict__ outb) {
    __shared__ u16 ldsA[128 * 32];
    __shared__ u16 ldsB[128 * 32];
    f32x4 acc[4][4];
#pragma unroll
    for (int i = 0; i < 4; ++i)
#pragma unroll
        for (int j = 0; j < 4; ++j) acc[i][j] = (f32x4){0.f, 0.f, 0.f, 0.f};
    int o0 = blockIdx.x * 128;
    size_t prow0 = (size_t)blockIdx.y * 128;
    gemm_mainloop(Wb, X, 256, o0, prow0, ldsA, ldsB, acc);

    int lane = threadIdx.x & 63, w = threadIdx.x >> 6;
    int wo = (w >> 1) * 64, wp = (w & 1) * 64;
    int quad = lane >> 4, cn = lane & 15;
#pragma unroll
    for (int i = 0; i < 4; ++i) {
        int ob = o0 + wo + i * 16 + quad * 4;
        f32x4 s4 = *(const f32x4*)&s[ob];
        f32x4 b4 = *(const f32x4*)&bb[ob];
#pragma unroll
        for (int j = 0; j < 4; ++j) {
            size_t p = prow0 + wp + j * 16 + cn;
            ushort4 o4;
            o4.x = f2bf(acc[i][j][0] * s4[0] + b4[0]);
            o4.y = f2bf(acc[i][j][1] * s4[1] + b4[1]);
            o4.z = f2bf(acc[i][j][2] * s4[2] + b4[2]);
            o4.w = f2bf(acc[i][j][3] * s4[3] + b4[3]);
            *(ushort4*)&outb[p * 256 + ob] = o4;
        }
    }
}

// ------------- FUSED DW+PW: one block = 64 p-rows (= one (b,h) row, all w).
__global__ __launch_bounds__(512, 4) void fused_dwpw(
    const u16* __restrict__ sc, const float* __restrict__ wdwT,
    const float* __restrict__ sdw, const float* __restrict__ bdw,
    const u16* __restrict__ Wpw,
    const float* __restrict__ spw, const float* __restrict__ bpw,
    u16* __restrict__ gate) {
    __shared__ u16 dwt[64 * 256];  // 32 KiB swizzled dw-output tile

    int t = threadIdx.x;
    int lane = t & 63, w = t >> 6;
    int quad = lane >> 4, cn = lane & 15;
    int p0 = blockIdx.x * 64;
    int h = (p0 >> 6) & 63;  // uniform over block

    // ---------------- phase A: dw 3x3, 4 (p,8ch) tasks per thread
#pragma unroll
    for (int kq = 0; kq < 4; ++kq) {
        int task = t + kq * 512;        // 0..2047
        int p_l = task >> 5;            // 0..63 == w index
        int cg = (task & 31) * 8;       // channel octet base
        size_t p = (size_t)p0 + p_l;
        float acc[8] = {0.f, 0.f, 0.f, 0.f, 0.f, 0.f, 0.f, 0.f};
#pragma unroll
        for (int ky = 0; ky < 3; ++ky) {
            int hh = h + ky - 1;
            if (hh < 0 || hh > 63) continue;
#pragma unroll
            for (int kx = 0; kx < 3; ++kx) {
                int wx = p_l + kx - 1;
                if (wx < 0 || wx > 63) continue;
                size_t pp = (size_t)((long long)p + (ky - 1) * 64 + (kx - 1));
                short8 v = *(const short8*)&sc[pp * 256 + cg];
                const float* wt = &wdwT[(ky * 3 + kx) * 256 + cg];
                f32x4 w0 = *(const f32x4*)wt;
                f32x4 w1 = *(const f32x4*)(wt + 4);
                acc[0] += w0[0] * bf2f((u16)v[0]); acc[1] += w0[1] * bf2f((u16)v[1]);
                acc[2] += w0[2] * bf2f((u16)v[2]); acc[3] += w0[3] * bf2f((u16)v[3]);
                acc[4] += w1[0] * bf2f((u16)v[4]); acc[5] += w1[1] * bf2f((u16)v[5]);
                acc[6] += w1[2] * bf2f((u16)v[6]); acc[7] += w1[3] * bf2f((u16)v[7]);
            }
        }
        f32x4 s0 = *(const f32x4*)&sdw[cg], s1 = *(const f32x4*)&sdw[cg + 4];
        f32x4 b0 = *(const f32x4*)&bdw[cg], b1 = *(const f32x4*)&bdw[cg + 4];
        short8 o;
        o[0] = (short)f2bf(fmaxf(acc[0] * s0[0] + b0[0], 0.f));
        o[1] = (short)f2bf(fmaxf(acc[1] * s0[1] + b0[1], 0.f));
        o[2] = (short)f2bf(fmaxf(acc[2] * s0[2] + b0[2], 0.f));
        o[3] = (short)f2bf(fmaxf(acc[3] * s0[3] + b0[3], 0.f));
        o[4] = (short)f2bf(fmaxf(acc[4] * s1[0] + b1[0], 0.f));
        o[5] = (short)f2bf(fmaxf(acc[5] * s1[1] + b1[1], 0.f));
        o[6] = (short)f2bf(fmaxf(acc[6] * s1[2] + b1[2], 0.f));
        o[7] = (short)f2bf(fmaxf(acc[7] * s1[3] + b1[3], 0.f));
        int ko = cg >> 3;  // octet index 0..31
        *(short8*)&dwt[p_l * 256 + ((ko ^ (p_l & 7)) << 3)] = o;
    }
    __syncthreads();

    // ---------------- phase B: pw GEMM, wave w owns 32 o-rows x 64 p, K=256
    f32x4 acc2[2][4];
#pragma unroll
    for (int i = 0; i < 2; ++i)
#pragma unroll
        for (int j = 0; j < 4; ++j) acc2[i][j] = (f32x4){0.f, 0.f, 0.f, 0.f};

    int ow = w * 32;
    const u16* gA = Wpw + (size_t)(ow + cn) * 256 + quad * 8;

    for (int k0 = 0; k0 < 256; k0 += 32) {
        short8 a[2], b[4];
        a[0] = *(const short8*)(gA + k0);
        a[1] = *(const short8*)(gA + (size_t)16 * 256 + k0);
        int og = (k0 >> 3) + quad;
#pragma unroll
        for (int j = 0; j < 4; ++j) {
            int pl = j * 16 + cn;
            b[j] = *(const short8*)&dwt[pl * 256 + ((og ^ (pl & 7)) << 3)];
        }
#pragma unroll
        for (int i = 0; i < 2; ++i)
#pragma unroll
            for (int j = 0; j < 4; ++j)
                acc2[i][j] = __builtin_amdgcn_mfma_f32_16x16x32_bf16(a[i], b[j], acc2[i][j], 0, 0, 0);
    }

    // epilogue: h_sigmoid -> gate bf16 [p][256]
#pragma unroll
    for (int i = 0; i < 2; ++i) {
        int ob = ow + i * 16 + quad * 4;
        f32x4 s4 = *(const f32x4*)&spw[ob];
        f32x4 b4 = *(const f32x4*)&bpw[ob];
#pragma unroll
        for (int j = 0; j < 4; ++j) {
            size_t p = (size_t)p0 + j * 16 + cn;
            ushort4 o4;
            o4.x = f2bf(fminf(fmaxf(acc2[i][j][0] * s4[0] + b4[0] + 3.f, 0.f), 6.f) * (1.f / 6.f));
            o4.y = f2bf(fminf(fmaxf(acc2[i][j][1] * s4[1] + b4[1] + 3.f, 0.f), 6.f) * (1.f / 6.f));
            o4.z = f2bf(fminf(fmaxf(acc2[i][j][2] * s4[2] + b4[2] + 3.f, 0.f), 6.f) * (1.f / 6.f));
            o4.w = f2bf(fminf(fmaxf(acc2[i][j][3] * s4[3] + b4[3] + 3.f, 0.f), 6.f) * (1.f / 6.f));
            *(ushort4*)&gate[p * 256 + ob] = o4;
        }
    }
}

// ------------- FUSED v5 (reverted): 64-p blocks (1024), abt-overlays-X, 64 KiB LDS.
__global__ __launch_bounds__(512, 4) void fused_vproj(
    const u16* __restrict__ Wv, const u16* __restrict__ Wp,
    const u16* __restrict__ X,
    const float* __restrict__ sv, const float* __restrict__ bv,
    const float* __restrict__ xr2, const float* __restrict__ xc2,
    const float* __restrict__ sp, const float* __restrict__ bp,
    const u16* __restrict__ gate, float* __restrict__ out) {
    __shared__ u16 lds[64 * 512];  // 64 KiB; bytes [0,32K) = X-tile during phase 1

    int t = threadIdx.x;
    int lane = t & 63, w = t >> 6;
    int quad = lane >> 4, cn = lane & 15;
    int p0 = blockIdx.x * 64;
    int bi = p0 >> 12;
    int hh = (p0 >> 6) & 63;

    // ---- stage X tile [64 p][32 k-octets]; LDS[p][ko] = G[p][ko ^ (p&7)]
#pragma unroll
    for (int r = 0; r < 4; ++r) {
        int li = r * 512 + t;  // 16B-unit index 0..2047
        int p = li >> 5, ko = li & 31;
        gload16(X + ((size_t)(p0 + p)) * 256 + ((ko ^ (p & 7)) << 3),
                lds + (size_t)li * 8);
    }
    __syncthreads();

    // ---------------- phase 1: V-GEMM, 8 waves x (64o x 64p), K=256.
    f32x4 acc1[4][4];
#pragma unroll
    for (int i = 0; i < 4; ++i)
#pragma unroll
        for (int j = 0; j < 4; ++j) acc1[i][j] = (f32x4){0.f, 0.f, 0.f, 0.f};

    int ow = w * 64;
    const u16* gA = Wv + (size_t)(ow + cn) * 256 + quad * 8;

    short8 a_c[4];
#pragma unroll
    for (int i = 0; i < 4; ++i) a_c[i] = *(const short8*)(gA + (size_t)i * 16 * 256);

#pragma unroll
    for (int kk = 0; kk < 8; ++kk) {
        int k0 = kk * 32;
        short8 a_n[4];
        if (kk < 7) {
#pragma unroll
            for (int i = 0; i < 4; ++i)
                a_n[i] = *(const short8*)(gA + (size_t)i * 16 * 256 + k0 + 32);
        }
        int og = (k0 >> 3) + quad;
        short8 b[4];
#pragma unroll
        for (int j = 0; j < 4; ++j) {
            int pl = j * 16 + cn;
            b[j] = *(const short8*)&lds[pl * 256 + ((og ^ (pl & 7)) << 3)];
        }
#pragma unroll
        for (int i = 0; i < 4; ++i)
#pragma unroll
            for (int j = 0; j < 4; ++j)
                acc1[i][j] = __builtin_amdgcn_mfma_f32_16x16x32_bf16(a_c[i], b[j], acc1[i][j], 0, 0, 0);
        if (kk < 7) {
#pragma unroll
            for (int i = 0; i < 4; ++i) a_c[i] = a_n[i];
        }
    }

    __syncthreads();  // all X reads done; abt may overwrite the region

    // epilogue 1: + sv/bv + xr + xc, relu -> bf16 -> swizzled abt
#pragma unroll
    for (int i = 0; i < 4; ++i) {
        int ob = ow + i * 16 + quad * 4;
        f32x4 s4 = *(const f32x4*)&sv[ob];
        f32x4 b4 = *(const f32x4*)&bv[ob];
        f32x4 ra = *(const f32x4*)&xr2[(size_t)bi * 32768 + hh * 512 + ob];
#pragma unroll
        for (int j = 0; j < 4; ++j) {
            int p = j * 16 + cn;  // local p == ww (p0 is 64-aligned)
            f32x4 ca = *(const f32x4*)&xc2[(size_t)bi * 32768 + p * 512 + ob];
            ushort4 o4;
            o4.x = f2bf(fmaxf(acc1[i][j][0] * s4[0] + b4[0] + ra[0] + ca[0], 0.f));
            o4.y = f2bf(fmaxf(acc1[i][j][1] * s4[1] + b4[1] + ra[1] + ca[1], 0.f));
            o4.z = f2bf(fmaxf(acc1[i][j][2] * s4[2] + b4[2] + ra[2] + ca[2], 0.f));
            o4.w = f2bf(fmaxf(acc1[i][j][3] * s4[3] + b4[3] + ra[3] + ca[3], 0.f));
            *(ushort4*)&lds[p * 512 + (ob ^ ((p & 7) << 3))] = o4;
        }
    }
    __syncthreads();  // abt complete

    // ---------------- phase 2: proj GEMM, 8 waves x (32o2 x 64p), K=512.
    f32x4 acc2[2][4];
#pragma unroll
    for (int i = 0; i < 2; ++i)
#pragma unroll
        for (int j = 0; j < 4; ++j) acc2[i][j] = (f32x4){0.f, 0.f, 0.f, 0.f};

    int o2w = w * 32;
    const u16* gP = Wp + (size_t)(o2w + cn) * 512 + quad * 8;

    short8 a2_c[2], b2_c[4];
#pragma unroll
    for (int i = 0; i < 2; ++i) a2_c[i] = *(const short8*)(gP + (size_t)i * 16 * 512);
    {
        int kk0 = quad * 8;
#pragma unroll
        for (int j = 0; j < 4; ++j) {
            int p = j * 16 + cn;
            b2_c[j] = *(const short8*)&lds[p * 512 + (kk0 ^ ((p & 7) << 3))];
        }
    }

#pragma unroll
    for (int kk = 0; kk < 16; ++kk) {
        short8 a2_n[2], b2_n[4];
        if (kk < 15) {
            int k1 = kk * 32 + 32;
#pragma unroll
            for (int i = 0; i < 2; ++i)
                a2_n[i] = *(const short8*)(gP + (size_t)i * 16 * 512 + k1);
            int kn = k1 + quad * 8;
#pragma unroll
            for (int j = 0; j < 4; ++j) {
                int p = j * 16 + cn;
                b2_n[j] = *(const short8*)&lds[p * 512 + (kn ^ ((p & 7) << 3))];
            }
        }
#pragma unroll
        for (int i = 0; i < 2; ++i)
#pragma unroll
            for (int j = 0; j < 4; ++j)
                acc2[i][j] = __builtin_amdgcn_mfma_f32_16x16x32_bf16(a2_c[i], b2_c[j], acc2[i][j], 0, 0, 0);
        if (kk < 15) {
#pragma unroll
            for (int i = 0; i < 2; ++i) a2_c[i] = a2_n[i];
#pragma unroll
            for (int j = 0; j < 4; ++j) b2_c[j] = b2_n[j];
        }
    }

    // epilogue 2: gate * (acc*s + b) -> out[b][o][p] fp32 (64B-line coalesced over cn)
    int pl0 = p0 & 4095;
#pragma unroll
    for (int i = 0; i < 2; ++i) {
        int ob = o2w + i * 16 + quad * 4;
        f32x4 s4 = *(const f32x4*)&sp[ob];
        f32x4 b4 = *(const f32x4*)&bp[ob];
#pragma unroll
        for (int j = 0; j < 4; ++j) {
            int p = j * 16 + cn;
            size_t pg = (size_t)p0 + p;
            ushort4 gv = *(const ushort4*)&gate[pg * 256 + ob];
            float* op = out + (size_t)bi * 1048576 + (size_t)ob * 4096 + (pl0 + p);
            op[0 * 4096] = bf2f(gv.x) * (acc2[i][j][0] * s4[0] + b4[0]);
            op[1 * 4096] = bf2f(gv.y) * (acc2[i][j][1] * s4[1] + b4[1]);
            op[2 * 4096] = bf2f(gv.z) * (acc2[i][j][2] * s4[2] + b4[2]);
            op[3 * 4096] = bf2f(gv.w) * (acc2[i][j][3] * s4[3] + b4[3]);
        }
    }
}

extern "C" void kernel_launch(void* const* d_in, const int* in_sizes, int n_in,
                              void* d_out, int out_size, void* d_ws, size_t ws_size,
                              hipStream_t stream) {
    const float* x = (const float*)d_in[0];
    const float* wq = (const float*)d_in[1];
    const float* sq = (const float*)d_in[2];
    const float* bq = (const float*)d_in[3];
    const float* wk = (const float*)d_in[4];
    const float* sk = (const float*)d_in[5];
    const float* bk = (const float*)d_in[6];
    const float* wv = (const float*)d_in[7];
    const float* sv = (const float*)d_in[8];
    const float* bv = (const float*)d_in[9];
    const float* posrq = (const float*)d_in[10];
    const float* posrk = (const float*)d_in[11];
    const float* poscq = (const float*)d_in[12];
    const float* posck = (const float*)d_in[13];
    const float* w_row = (const float*)d_in[14];
    const float* s_row = (const float*)d_in[15];
    const float* b_row = (const float*)d_in[16];
    const float* w_col = (const float*)d_in[17];
    const float* s_col = (const float*)d_in[18];
    const float* b_col = (const float*)d_in[19];
    const float* w_proj = (const float*)d_in[20];
    const float* s_proj = (const float*)d_in[21];
    const float* b_proj = (const float*)d_in[22];
    const float* w_sc = (const float*)d_in[23];
    const float* s_sc = (const float*)d_in[24];
    const float* b_sc = (const float*)d_in[25];
    const float* w_dw = (const float*)d_in[26];
    const float* s_dw = (const float*)d_in[27];
    const float* b_dw = (const float*)d_in[28];
    const float* w_pw = (const float*)d_in[29];
    const float* s_pw = (const float*)d_in[30];
    const float* b_pw = (const float*)d_in[31];
    float* out = (float*)d_out;

    float* fws = (float*)d_ws;
    float* qrow = fws;                   // [b][c=128][n] fp32
    float* krow = qrow + 131072;
    float* qcol = krow + 131072;
    float* kcol = qcol + 131072;
    float* vrow = kcol + 131072;         // [b][c=512][n]
    float* vcol = vrow + 524288;
    float* xr2  = vcol + 524288;         // [b][n][512] fp32
    float* xc2  = xr2 + 524288;
    float* wdwT = xc2 + 524288;          // [9][256]
    u16* xmb    = (u16*)(wdwT + 2304);            // [2048][256] bf16 means
    u16* xbf    = xmb + 524288;                   // [65536][256]
    u16* wqkvb  = xbf + (size_t)PTOT * 256;       // [768][256]
    u16* wscb   = wqkvb + 196608;                 // [256][256]
    u16* wprojb = wscb + 65536;                   // [256][512]
    u16* wpwb   = wprojb + 131072;                // [256][256]
    u16* wrb    = wpwb + 65536;                   // [512][512]
    u16* wcb    = wrb + 262144;                   // [512][512]
    u16* xxbf   = wcb + 262144;                   // [b][br][64][512]
    u16* scb    = xxbf + 1048576;                 // [65536][256]
    u16* gate   = scb + (size_t)PTOT * 256;       // [65536][256]

    mean_kernel<<<dim3(Bn * Cc), 256, 0, stream>>>(x, xmb);
    xpose_kernel<<<dim3(64, 4, Bn), 256, 0, stream>>>(x, xbf);
    wconv_kernel<<<dim3(3840), 256, 0, stream>>>(
        wq, wk, wv, w_sc, w_proj, w_pw, w_row, w_col, w_dw,
        wqkvb, wscb, wprojb, wpwb, wrb, wcb, wdwT);
    gemm_qkv<<<dim3(6, 16), 256, 0, stream>>>(
        wqkvb, xmb, sq, bq, sk, bk, sv, bv,
        posrq, posrk, poscq, posck, qrow, krow, vrow, qcol, kcol, vcol);
    attn_kernel<<<dim3(128, 2), 512, 0, stream>>>(qrow, krow, vrow, qcol, kcol, vcol, xxbf);
    post_gemm<<<dim3(4, Bn, 2), 256, 0, stream>>>(
        xxbf, wrb, wcb, s_row, b_row, s_col, b_col, xr2, xc2);
    gemm_sc<<<dim3(2, 512), 256, 0, stream>>>(wscb, xbf, s_sc, b_sc, scb);
    fused_dwpw<<<dim3(1024), 512, 0, stream>>>(
        scb, wdwT, s_dw, b_dw, wpwb, s_pw, b_pw, gate);
    fused_vproj<<<dim3(1024), 512, 0, stream>>>(
        wqkvb + 65536, wprojb, xbf, sv, bv, xr2, xc2, s_proj, b_proj, gate, out);
}